// Round 2
// baseline (11233.723 us; speedup 1.0000x reference)
//
#include <hip/hip_runtime.h>
#include <hip/hip_bf16.h>

// ProductGraphsModel: 2x256 independent 5-layer GCN stacks + mean-pool + FC.
// Round 2 design:
//  - prep: per-instance degree/norm + CSR-by-dst (counting sort).
//  - dense H x H transforms: bf16 MFMA with 3-term hi/lo split (~1e-5 rel err).
//    A (activations) stored split by agg epilogue; W transposed+split once.
//    GEMM: BM=128, BN=256(all of N), BK=32, 8 waves, global_load_lds staging.
//  - agg: CSR gather lane=channel, fused bias+relu, writes bf16 hi/lo.
//  - pool reconstructs hi+lo; tiny FC head.

#define G_   256
#define N_   512
#define E_   16384
#define H_   256
#define FIN  4
#define FG   6
#define C_   3
#define L_   5
#define B_   512   // 2*G_ instances (home then away)

typedef __attribute__((ext_vector_type(4))) float f32x4;
typedef __attribute__((ext_vector_type(8))) short bf16x8;

__device__ __forceinline__ void gload_lds16(const void* g, void* l) {
    __builtin_amdgcn_global_load_lds(
        (const __attribute__((address_space(1))) void*)g,
        (__attribute__((address_space(3))) void*)l, 16, 0, 0);
}

// ---------------------------------------------------------------- prep ----
__global__ __launch_bounds__(256) void prep_kernel(
    const int* __restrict__ hei, const int* __restrict__ aei,
    const float* __restrict__ hew, const float* __restrict__ aew,
    int inst0,
    int* __restrict__ colv, float* __restrict__ valv,
    int* __restrict__ rowptr, float* __restrict__ selfnorm)
{
    const int ci = blockIdx.x;
    const int b  = inst0 + ci;
    const int g  = (b < G_) ? b : b - G_;
    const int*   ei = ((b < G_) ? hei : aei) + (size_t)g * 2 * E_;
    const float* ew = ((b < G_) ? hew : aew) + (size_t)g * E_;
    const int* srcA = ei;
    const int* dstA = ei + E_;

    __shared__ float degS[N_];
    __shared__ int   cntS[N_];
    __shared__ int   startS[N_ + 1];
    __shared__ int   curS[N_];
    const int tid = threadIdx.x;

    for (int n = tid; n < N_; n += 256) { degS[n] = 1.0f; cntS[n] = 0; }  // self-loop weight 1
    __syncthreads();
    for (int e = tid; e < E_; e += 256) {
        atomicAdd(&degS[dstA[e]], ew[e]);
        atomicAdd(&cntS[dstA[e]], 1);
    }
    __syncthreads();
    for (int n = tid; n < N_; n += 256) {
        float dinv = rsqrtf(degS[n]);
        degS[n] = dinv;
        selfnorm[(size_t)ci * N_ + n] = dinv * dinv;
    }
    __syncthreads();
    if (tid == 0) {
        int acc = 0;
        for (int n = 0; n < N_; ++n) { startS[n] = acc; acc += cntS[n]; }
        startS[N_] = acc;
    }
    __syncthreads();
    for (int n = tid; n <= N_; n += 256) rowptr[(size_t)ci * (N_ + 1) + n] = startS[n];
    for (int n = tid; n < N_; n += 256)  curS[n] = 0;
    __syncthreads();
    for (int e = tid; e < E_; e += 256) {
        int t = dstA[e], s = srcA[e];
        int pos = startS[t] + atomicAdd(&curS[t], 1);
        colv[(size_t)ci * E_ + pos] = s;
        valv[(size_t)ci * E_ + pos] = degS[s] * ew[e] * degS[t];
    }
}

// ------------------------------------------------ W transpose + split ----
// Wh[l][k][n] fp32 -> WThi/WTlo[l][n][k] bf16 (hi + lo = W to ~2^-17 rel).
__global__ __launch_bounds__(256) void wsplit_kernel(
    const float* __restrict__ Wh,
    __hip_bfloat16* __restrict__ WThi, __hip_bfloat16* __restrict__ WTlo)
{
    const int idx = blockIdx.x * 256 + threadIdx.x;      // l*65536 + n*256 + k
    if (idx >= (L_ - 1) * H_ * H_) return;
    const int l = idx >> 16, rem = idx & 65535;
    const int n = rem >> 8, k = rem & 255;
    const float w = Wh[(size_t)l * H_ * H_ + (size_t)k * H_ + n];
    const __hip_bfloat16 hi = __float2bfloat16(w);
    WThi[idx] = hi;
    WTlo[idx] = __float2bfloat16(w - __bfloat162float(hi));
}

// ---------------------------------------------------- layer-0 transform ----
__global__ __launch_bounds__(256) void xw0_kernel(
    const float* __restrict__ hx, const float* __restrict__ ax,
    const float* __restrict__ W0, int inst0, float* __restrict__ h0)
{
    const size_t idx = (size_t)blockIdx.x * 256 + threadIdx.x;
    const int    c   = (int)(idx & (H_ - 1));
    const size_t nn  = idx >> 8;
    const int    ci  = (int)(nn / N_);
    const int    n   = (int)(nn % N_);
    const int    b   = inst0 + ci;
    const int    g   = (b < G_) ? b : b - G_;
    const float* x = ((b < G_) ? hx : ax) + ((size_t)g * N_ + n) * FIN;
    float acc = 0.f;
#pragma unroll
    for (int k = 0; k < FIN; ++k) acc += x[k] * W0[k * H_ + c];
    h0[idx] = acc;
}

// -------------------------------------------------- bf16-split MFMA GEMM ----
// C[M,256] = (Ahi+Alo)[M,256] @ (W)[256,256] via hi*hi + hi*lo + lo*hi.
// B source is WT[n][k]. BM=128, BN=256, BK=32, 512 threads (8 waves, 2x4),
// wave tile 64x64 = 4x4 fragments of 16x16x32. LDS staged via global_load_lds,
// layout [kb][row][8] (lane reads 16B at consecutive rows: conflict-free).
__global__ __launch_bounds__(512) void gemm_mfma_kernel(
    const __hip_bfloat16* __restrict__ Ahi_, const __hip_bfloat16* __restrict__ Alo_,
    const __hip_bfloat16* __restrict__ Whi_, const __hip_bfloat16* __restrict__ Wlo_,
    float* __restrict__ Cout)
{
    __shared__ short lA[2][4 * 128 * 8];   // 16 KiB  (split, kb, row(m), 8k)
    __shared__ short lB[2][4 * 256 * 8];   // 32 KiB  (split, kb, row(n), 8k)
    const short* Ag[2] = { (const short*)Ahi_, (const short*)Alo_ };
    const short* Bg[2] = { (const short*)Whi_, (const short*)Wlo_ };

    const int tid  = threadIdx.x;
    const int lane = tid & 63;
    const int wave = tid >> 6;
    const int wm   = (wave >> 2) * 64;     // 0,64
    const int wn   = (wave & 3) * 64;      // 0,64,128,192
    const int m0   = blockIdx.x * 128;
    const int l15  = lane & 15;
    const int kb4  = lane >> 4;

    f32x4 acc[4][4];
#pragma unroll
    for (int i = 0; i < 4; ++i)
#pragma unroll
        for (int j = 0; j < 4; ++j) acc[i][j] = (f32x4)0.f;

    for (int k0 = 0; k0 < 256; k0 += 32) {
        // --- stage A: 512 chunks/split (1 call), B: 1024 chunks/split (2 calls)
#pragma unroll
        for (int s = 0; s < 2; ++s) {
            {
                const int c = tid;                       // 0..511
                const int row = c & 127, kb = c >> 7;
                gload_lds16(Ag[s] + (((size_t)(m0 + row)) << 8) + k0 + (kb << 3),
                            &lA[s][(c & ~63) << 3]);
            }
#pragma unroll
            for (int call = 0; call < 2; ++call) {
                const int c = call * 512 + tid;          // 0..1023
                const int row = c & 255, kb = c >> 8;
                gload_lds16(Bg[s] + (((size_t)row) << 8) + k0 + (kb << 3),
                            &lB[s][(c & ~63) << 3]);
            }
        }
        __syncthreads();

        bf16x8 ah[4], al[4];
#pragma unroll
        for (int mf = 0; mf < 4; ++mf) {
            const int r = wm + mf * 16 + l15;
            ah[mf] = *(const bf16x8*)&lA[0][(kb4 * 128 + r) << 3];
            al[mf] = *(const bf16x8*)&lA[1][(kb4 * 128 + r) << 3];
        }
#pragma unroll
        for (int nf = 0; nf < 4; ++nf) {
            const int r = wn + nf * 16 + l15;
            const bf16x8 bh = *(const bf16x8*)&lB[0][(kb4 * 256 + r) << 3];
            const bf16x8 bl = *(const bf16x8*)&lB[1][(kb4 * 256 + r) << 3];
#pragma unroll
            for (int mf = 0; mf < 4; ++mf) {
                acc[mf][nf] = __builtin_amdgcn_mfma_f32_16x16x32_bf16(ah[mf], bh, acc[mf][nf], 0, 0, 0);
                acc[mf][nf] = __builtin_amdgcn_mfma_f32_16x16x32_bf16(ah[mf], bl, acc[mf][nf], 0, 0, 0);
                acc[mf][nf] = __builtin_amdgcn_mfma_f32_16x16x32_bf16(al[mf], bh, acc[mf][nf], 0, 0, 0);
            }
        }
        __syncthreads();
    }

    // epilogue: D row=(lane>>4)*4+j, col=lane&15
#pragma unroll
    for (int mf = 0; mf < 4; ++mf) {
        const int r0 = m0 + wm + mf * 16 + (kb4 << 2);
#pragma unroll
        for (int nf = 0; nf < 4; ++nf) {
            const int col = wn + nf * 16 + l15;
            const f32x4 v = acc[mf][nf];
#pragma unroll
            for (int j = 0; j < 4; ++j)
                Cout[((size_t)(r0 + j) << 8) + col] = v[j];
        }
    }
}

// ---------------------------------------------------------- aggregation ----
// out[t][c] = relu( selfnorm[t]*h[t][c] + sum val[e]*h[col[e]][c] + bias[c] )
// written as bf16 hi/lo split for the next MFMA GEMM.
__global__ __launch_bounds__(256) void agg_kernel(
    const float* __restrict__ h, const int* __restrict__ colv,
    const float* __restrict__ valv, const int* __restrict__ rowptr,
    const float* __restrict__ selfnorm, const float* __restrict__ bias,
    __hip_bfloat16* __restrict__ xhi, __hip_bfloat16* __restrict__ xlo)
{
    const int ci = blockIdx.y;
    const int t0 = blockIdx.x * 32;
    const int c  = threadIdx.x;
    const float* hb = h + (size_t)ci * N_ * H_;
    const int*   rp = rowptr + (size_t)ci * (N_ + 1);
    const int*   cv = colv + (size_t)ci * E_;
    const float* vv = valv + (size_t)ci * E_;
    const float bval = bias[c];
    for (int i = 0; i < 32; ++i) {
        const int t = t0 + i;
        float acc = selfnorm[(size_t)ci * N_ + t] * hb[(size_t)t * H_ + c];
        const int r0 = rp[t], r1 = rp[t + 1];
        for (int e = r0; e < r1; ++e)
            acc += vv[e] * hb[(size_t)cv[e] * H_ + c];
        const float v = fmaxf(acc + bval, 0.0f);
        const __hip_bfloat16 hi = __float2bfloat16(v);
        const size_t o = ((size_t)ci * N_ + t) * H_ + c;
        xhi[o] = hi;
        xlo[o] = __float2bfloat16(v - __bfloat162float(hi));
    }
}

// ----------------------------------------------------------------- pool ----
__global__ __launch_bounds__(256) void pool_kernel(
    const __hip_bfloat16* __restrict__ xhi, const __hip_bfloat16* __restrict__ xlo,
    int inst0, float* __restrict__ pooled)
{
    const int ci = blockIdx.x;
    const int c  = threadIdx.x;
    const __hip_bfloat16* xh = xhi + (size_t)ci * N_ * H_;
    const __hip_bfloat16* xl = xlo + (size_t)ci * N_ * H_;
    float acc = 0.f;
    for (int n = 0; n < N_; ++n)
        acc += __bfloat162float(xh[(size_t)n * H_ + c]) + __bfloat162float(xl[(size_t)n * H_ + c]);
    pooled[(size_t)(inst0 + ci) * H_ + c] = acc * (1.0f / N_);
}

// ------------------------------------------------------------------- fc ----
__global__ __launch_bounds__(256) void fc_kernel(
    const float* __restrict__ pooled, const float* __restrict__ hf,
    const float* __restrict__ af, const float* __restrict__ fcW,
    const float* __restrict__ fcb, float* __restrict__ outp)
{
    const int idx = blockIdx.x * 256 + threadIdx.x;
    if (idx >= G_ * C_) return;
    const int gi = idx / C_;
    const int c  = idx % C_;
    float acc = fcb[c];
    const float* ph = pooled + (size_t)gi * H_;
    const float* pa = pooled + (size_t)(G_ + gi) * H_;
    for (int j = 0; j < H_; ++j) acc += ph[j] * fcW[j * C_ + c];
    for (int j = 0; j < FG; ++j) acc += hf[gi * FG + j] * fcW[(H_ + j) * C_ + c];
    for (int j = 0; j < H_; ++j) acc += pa[j] * fcW[(H_ + FG + j) * C_ + c];
    for (int j = 0; j < FG; ++j) acc += af[gi * FG + j] * fcW[(H_ + FG + H_ + j) * C_ + c];
    outp[idx] = acc;
}

// ----------------------------------------------------------------- host ----
static inline size_t align_up(size_t v, size_t a) { return (v + a - 1) & ~(a - 1); }

extern "C" void kernel_launch(void* const* d_in, const int* in_sizes, int n_in,
                              void* d_out, int out_size, void* d_ws, size_t ws_size,
                              hipStream_t stream)
{
    const float* hx  = (const float*)d_in[0];
    const float* ax  = (const float*)d_in[1];
    const int*   hei = (const int*)d_in[2];
    const int*   aei = (const int*)d_in[3];
    const float* hew = (const float*)d_in[4];
    const float* aew = (const float*)d_in[5];
    const float* hf  = (const float*)d_in[6];
    const float* af  = (const float*)d_in[7];
    const float* W0  = (const float*)d_in[8];
    const float* Wh  = (const float*)d_in[9];
    const float* bs  = (const float*)d_in[10];
    const float* fcW = (const float*)d_in[11];
    const float* fcb = (const float*)d_in[12];
    float* outp = (float*)d_out;

    const size_t pooled_b = align_up((size_t)B_ * H_ * sizeof(float), 256);
    const size_t wt_b     = align_up((size_t)(L_ - 1) * H_ * H_ * sizeof(__hip_bfloat16), 256);
    const size_t col_b  = align_up((size_t)E_ * sizeof(int), 256);
    const size_t val_b  = align_up((size_t)E_ * sizeof(float), 256);
    const size_t rp_b   = align_up((size_t)(N_ + 1) * sizeof(int), 256);
    const size_t sn_b   = align_up((size_t)N_ * sizeof(float), 256);
    const size_t h_b    = align_up((size_t)N_ * H_ * sizeof(float), 256);
    const size_t xs_b   = align_up((size_t)N_ * H_ * sizeof(__hip_bfloat16), 256);
    const size_t per_inst = col_b + val_b + rp_b + sn_b + h_b + 2 * xs_b;
    const size_t fixed = pooled_b + 2 * wt_b;

    int CB = (int)((ws_size > fixed) ? (ws_size - fixed) / per_inst : 0);
    if (CB < 1) CB = 1;
    if (CB > B_) CB = B_;

    char* p = (char*)d_ws;
    float* pooled = (float*)p;               p += pooled_b;
    __hip_bfloat16* WThi = (__hip_bfloat16*)p; p += wt_b;
    __hip_bfloat16* WTlo = (__hip_bfloat16*)p; p += wt_b;
    int*   colv = (int*)p;                   p += (size_t)CB * col_b;
    float* valv = (float*)p;                 p += (size_t)CB * val_b;
    int*   rowptr = (int*)p;                 p += (size_t)CB * rp_b;
    float* selfnorm = (float*)p;             p += (size_t)CB * sn_b;
    float* hbuf = (float*)p;                 p += (size_t)CB * h_b;
    __hip_bfloat16* xhi = (__hip_bfloat16*)p; p += (size_t)CB * xs_b;
    __hip_bfloat16* xlo = (__hip_bfloat16*)p;

    wsplit_kernel<<<((L_ - 1) * H_ * H_ + 255) / 256, 256, 0, stream>>>(Wh, WThi, WTlo);

    for (int i0 = 0; i0 < B_; i0 += CB) {
        const int cb = (B_ - i0 < CB) ? (B_ - i0) : CB;

        prep_kernel<<<cb, 256, 0, stream>>>(hei, aei, hew, aew, i0,
                                            colv, valv, rowptr, selfnorm);
        xw0_kernel<<<cb * (N_ * H_ / 256), 256, 0, stream>>>(hx, ax, W0, i0, hbuf);

        for (int l = 0; l < L_; ++l) {
            if (l > 0) {
                gemm_mfma_kernel<<<cb * (N_ / 128), 512, 0, stream>>>(
                    xhi, xlo,
                    WThi + (size_t)(l - 1) * H_ * H_,
                    WTlo + (size_t)(l - 1) * H_ * H_,
                    hbuf);
            }
            agg_kernel<<<dim3(N_ / 32, cb), 256, 0, stream>>>(
                hbuf, colv, valv, rowptr, selfnorm, bs + (size_t)l * H_, xhi, xlo);
        }
        pool_kernel<<<cb, 256, 0, stream>>>(xhi, xlo, i0, pooled);
    }

    fc_kernel<<<(G_ * C_ + 255) / 256, 256, 0, stream>>>(pooled, hf, af, fcW, fcb, outp);
}

// Round 4
// 8400.182 us; speedup vs baseline: 1.3373x; 1.3373x over previous
//
#include <hip/hip_runtime.h>
#include <hip/hip_bf16.h>

// ProductGraphsModel: 2x256 independent 5-layer GCN stacks + mean-pool + FC.
// Round 4: = round 3 with the agg LDS-staging underfill fixed (it<4 -> it<16:
// hs is 8192 16B chunks, not 2048 — rows 128..511 were stale LDS).
//  - agg: LDS-staged gather (block = instance x 64-ch chunk, 128 KiB LDS),
//    readlane edge broadcast, XCD-chunk swizzle.
//  - GEMM: bf16 3-term split, BM=BN=128, 256 thr, double-buffered LDS,
//    2-phase schedule, XCD swizzle pairing n-blocks.

#define G_   256
#define N_   512
#define E_   16384
#define H_   256
#define FIN  4
#define FG   6
#define C_   3
#define L_   5
#define B_   512   // 2*G_ instances (home then away)

typedef __attribute__((ext_vector_type(4))) float f32x4;
typedef __attribute__((ext_vector_type(8))) short bf16x8;

__device__ __forceinline__ void gload_lds16(const void* g, void* l) {
    __builtin_amdgcn_global_load_lds(
        (const __attribute__((address_space(1))) void*)g,
        (__attribute__((address_space(3))) void*)l, 16, 0, 0);
}

// m204 bijective chunked swizzle: orig%8 = HW XCD; contiguous work-ids land
// on one XCD so blocks sharing data share an L2.
__device__ __forceinline__ int xcd_chunk_swizzle(int orig, int nwg) {
    const int q = nwg >> 3, r = nwg & 7, x = orig & 7;
    const int base = (x < r) ? x * (q + 1) : r * (q + 1) + (x - r) * q;
    return base + (orig >> 3);
}

// ---------------------------------------------------------------- prep ----
__global__ __launch_bounds__(256) void prep_kernel(
    const int* __restrict__ hei, const int* __restrict__ aei,
    const float* __restrict__ hew, const float* __restrict__ aew,
    int inst0,
    int* __restrict__ colv, float* __restrict__ valv,
    int* __restrict__ rowptr, float* __restrict__ selfnorm)
{
    const int ci = blockIdx.x;
    const int b  = inst0 + ci;
    const int g  = (b < G_) ? b : b - G_;
    const int*   ei = ((b < G_) ? hei : aei) + (size_t)g * 2 * E_;
    const float* ew = ((b < G_) ? hew : aew) + (size_t)g * E_;
    const int* srcA = ei;
    const int* dstA = ei + E_;

    __shared__ float degS[N_];
    __shared__ int   cntS[N_];
    __shared__ int   startS[N_ + 1];
    __shared__ int   curS[N_];
    const int tid = threadIdx.x;

    for (int n = tid; n < N_; n += 256) { degS[n] = 1.0f; cntS[n] = 0; }  // self-loop weight 1
    __syncthreads();
    for (int e = tid; e < E_; e += 256) {
        atomicAdd(&degS[dstA[e]], ew[e]);
        atomicAdd(&cntS[dstA[e]], 1);
    }
    __syncthreads();
    for (int n = tid; n < N_; n += 256) {
        float dinv = rsqrtf(degS[n]);
        degS[n] = dinv;
        selfnorm[(size_t)ci * N_ + n] = dinv * dinv;
    }
    __syncthreads();
    if (tid == 0) {
        int acc = 0;
        for (int n = 0; n < N_; ++n) { startS[n] = acc; acc += cntS[n]; }
        startS[N_] = acc;
    }
    __syncthreads();
    for (int n = tid; n <= N_; n += 256) rowptr[(size_t)ci * (N_ + 1) + n] = startS[n];
    for (int n = tid; n < N_; n += 256)  curS[n] = 0;
    __syncthreads();
    for (int e = tid; e < E_; e += 256) {
        int t = dstA[e], s = srcA[e];
        int pos = startS[t] + atomicAdd(&curS[t], 1);
        colv[(size_t)ci * E_ + pos] = s;
        valv[(size_t)ci * E_ + pos] = degS[s] * ew[e] * degS[t];
    }
}

// ------------------------------------------------ W transpose + split ----
__global__ __launch_bounds__(256) void wsplit_kernel(
    const float* __restrict__ Wh,
    __hip_bfloat16* __restrict__ WThi, __hip_bfloat16* __restrict__ WTlo)
{
    const int idx = blockIdx.x * 256 + threadIdx.x;      // l*65536 + n*256 + k
    if (idx >= (L_ - 1) * H_ * H_) return;
    const int l = idx >> 16, rem = idx & 65535;
    const int n = rem >> 8, k = rem & 255;
    const float w = Wh[(size_t)l * H_ * H_ + (size_t)k * H_ + n];
    const __hip_bfloat16 hi = __float2bfloat16(w);
    WThi[idx] = hi;
    WTlo[idx] = __float2bfloat16(w - __bfloat162float(hi));
}

// ---------------------------------------------------- layer-0 transform ----
// block = 16 nodes of one instance; thread = channel.
__global__ __launch_bounds__(256) void xw0_kernel(
    const float* __restrict__ hx, const float* __restrict__ ax,
    const float* __restrict__ W0, int inst0, float* __restrict__ h0)
{
    const int ci = blockIdx.x >> 5;
    const int n0 = (blockIdx.x & 31) << 4;
    const int c  = threadIdx.x;
    const int b  = inst0 + ci;
    const int g  = (b < G_) ? b : b - G_;
    const float w0 = W0[c], w1 = W0[H_ + c], w2 = W0[2 * H_ + c], w3 = W0[3 * H_ + c];
    const float* x = ((b < G_) ? hx : ax) + ((size_t)g * N_ + n0) * FIN;
    float* o = h0 + (((size_t)ci * N_ + n0) << 8) + c;
#pragma unroll
    for (int i = 0; i < 16; ++i) {
        const float4 xv = *(const float4*)&x[i * 4];
        float acc = xv.x * w0;
        acc = fmaf(xv.y, w1, acc);
        acc = fmaf(xv.z, w2, acc);
        acc = fmaf(xv.w, w3, acc);
        o[(size_t)i << 8] = acc;
    }
}

// -------------------------------------------------- bf16-split MFMA GEMM ----
// C[M,256] = (Ahi+Alo) @ W via hi*hi + hi*lo + lo*hi. B source WT[n][k].
// BM=BN=128, BK=32, 256 threads (2x2 waves of 64x64), double-buffered LDS.
__global__ __launch_bounds__(256) void gemm_mfma_kernel(
    const __hip_bfloat16* __restrict__ Ahi_, const __hip_bfloat16* __restrict__ Alo_,
    const __hip_bfloat16* __restrict__ Whi_, const __hip_bfloat16* __restrict__ Wlo_,
    float* __restrict__ Cout)
{
    __shared__ short lA[2][2][4096];   // [buf][split][(kb*128+row)*8+j] : 16 KiB each
    __shared__ short lB[2][2][4096];
    const short* Ag[2] = { (const short*)Ahi_, (const short*)Alo_ };
    const short* Bg[2] = { (const short*)Whi_, (const short*)Wlo_ };

    const int tid  = threadIdx.x;
    const int w    = xcd_chunk_swizzle(blockIdx.x, gridDim.x);
    const int m0   = (w >> 1) * 128;
    const int n0   = (w & 1) * 128;
    const int lane = tid & 63;
    const int wave = tid >> 6;
    const int wm   = (wave >> 1) * 64;
    const int wn   = (wave & 1) * 64;
    const int l15  = lane & 15;
    const int kb4  = lane >> 4;

    f32x4 acc[4][4];
#pragma unroll
    for (int i = 0; i < 4; ++i)
#pragma unroll
        for (int j = 0; j < 4; ++j) acc[i][j] = (f32x4)0.f;

#define STAGE(buf, k0) do { \
    _Pragma("unroll") for (int s = 0; s < 2; ++s) { \
        _Pragma("unroll") for (int call = 0; call < 2; ++call) { \
            const int c = call * 256 + tid; \
            const int row = c & 127, kb = c >> 7; \
            gload_lds16(Ag[s] + (((size_t)(m0 + row)) << 8) + (k0) + (kb << 3), \
                        &lA[buf][s][(c & ~63) << 3]); \
            gload_lds16(Bg[s] + (((size_t)(n0 + row)) << 8) + (k0) + (kb << 3), \
                        &lB[buf][s][(c & ~63) << 3]); \
        } } } while (0)

#define COMPUTE(buf) do { \
    bf16x8 ah[4], al[4]; \
    _Pragma("unroll") for (int mf = 0; mf < 4; ++mf) { \
        const int r = kb4 * 128 + wm + mf * 16 + l15; \
        ah[mf] = *(const bf16x8*)&lA[buf][0][r << 3]; \
        al[mf] = *(const bf16x8*)&lA[buf][1][r << 3]; \
    } \
    _Pragma("unroll") for (int nf = 0; nf < 4; ++nf) { \
        const int r = kb4 * 128 + wn + nf * 16 + l15; \
        const bf16x8 bh = *(const bf16x8*)&lB[buf][0][r << 3]; \
        const bf16x8 bl = *(const bf16x8*)&lB[buf][1][r << 3]; \
        _Pragma("unroll") for (int mf = 0; mf < 4; ++mf) { \
            acc[mf][nf] = __builtin_amdgcn_mfma_f32_16x16x32_bf16(ah[mf], bh, acc[mf][nf], 0, 0, 0); \
            acc[mf][nf] = __builtin_amdgcn_mfma_f32_16x16x32_bf16(ah[mf], bl, acc[mf][nf], 0, 0, 0); \
            acc[mf][nf] = __builtin_amdgcn_mfma_f32_16x16x32_bf16(al[mf], bh, acc[mf][nf], 0, 0, 0); \
        } } } while (0)

    STAGE(0, 0);
    __syncthreads();
#pragma unroll
    for (int st = 0; st < 7; ++st) {
        STAGE((st + 1) & 1, (st + 1) * 32);   // async next tile
        COMPUTE(st & 1);                      // compute current
        __syncthreads();                      // drains vmcnt+lgkm: next ready, cur free
    }
    COMPUTE(1);

#pragma unroll
    for (int mf = 0; mf < 4; ++mf) {
        const int r0 = m0 + wm + mf * 16 + (kb4 << 2);
#pragma unroll
        for (int nf = 0; nf < 4; ++nf) {
            const int col = n0 + wn + nf * 16 + l15;
            const f32x4 v = acc[mf][nf];
#pragma unroll
            for (int j = 0; j < 4; ++j)
                Cout[((size_t)(r0 + j) << 8) + col] = v[j];
        }
    }
#undef STAGE
#undef COMPUTE
}

// ---------------------------------------------------------- aggregation ----
// block = (instance, 64-ch chunk); stage h[:, chunk] in LDS (128 KiB = 8192
// 16B chunks -> 16 staging iterations at 512 threads);
// per dst row: coalesced 64-edge load + readlane broadcast; lane = channel.
__global__ __launch_bounds__(512) void agg_kernel(
    const float* __restrict__ h, const int* __restrict__ colv,
    const float* __restrict__ valv, const int* __restrict__ rowptr,
    const float* __restrict__ selfnorm, const float* __restrict__ bias,
    __hip_bfloat16* __restrict__ xhi, __hip_bfloat16* __restrict__ xlo)
{
    __shared__ float hs[N_ * 64];   // 128 KiB: hs[n][c]
    const int w    = xcd_chunk_swizzle(blockIdx.x, gridDim.x);
    const int ci   = w >> 2;
    const int c0   = (w & 3) << 6;
    const int tid  = threadIdx.x;
    const int lane = tid & 63;
    const int wv   = tid >> 6;

    const float* hb = h + (size_t)ci * N_ * H_;
#pragma unroll
    for (int it = 0; it < 16; ++it) {           // 8192 16B chunks / 512 thr
        const int i  = it * 512 + tid;
        const int n  = i >> 4;
        const int c4 = (i & 15) << 2;
        gload_lds16(hb + (size_t)n * H_ + c0 + c4, &hs[(i & ~63) << 2]);
    }
    __syncthreads();

    const int*   rp = rowptr + (size_t)ci * (N_ + 1);
    const int*   cv = colv + (size_t)ci * E_;
    const float* vv = valv + (size_t)ci * E_;
    const float* sn = selfnorm + (size_t)ci * N_;
    const float bval = bias[c0 + lane];

    for (int t = wv * 64; t < wv * 64 + 64; ++t) {
        float acc = sn[t] * hs[t * 64 + lane];
        const int r1 = rp[t + 1];
        for (int e0 = rp[t]; e0 < r1; e0 += 64) {
            const int rem = r1 - e0;
            int mc = 0; float mv = 0.f;
            if (lane < rem) { mc = cv[e0 + lane]; mv = vv[e0 + lane]; }
            const int cnt = rem < 64 ? rem : 64;
            for (int i = 0; i < cnt; ++i) {
                const int s     = __builtin_amdgcn_readlane(mc, i);
                const int vbits = __builtin_amdgcn_readlane((int)__float_as_uint(mv), i);
                acc = fmaf(__uint_as_float((unsigned)vbits), hs[s * 64 + lane], acc);
            }
        }
        const float o = fmaxf(acc + bval, 0.f);
        const __hip_bfloat16 hi = __float2bfloat16(o);
        const size_t off = ((size_t)ci * N_ + t) * H_ + c0 + lane;
        xhi[off] = hi;
        xlo[off] = __float2bfloat16(o - __bfloat162float(hi));
    }
}

// ----------------------------------------------------------------- pool ----
__global__ __launch_bounds__(256) void pool_kernel(
    const __hip_bfloat16* __restrict__ xhi, const __hip_bfloat16* __restrict__ xlo,
    int inst0, float* __restrict__ pooled)
{
    const int ci = blockIdx.x;
    const int c  = threadIdx.x;
    const __hip_bfloat16* xh = xhi + (size_t)ci * N_ * H_;
    const __hip_bfloat16* xl = xlo + (size_t)ci * N_ * H_;
    float acc = 0.f;
    for (int n = 0; n < N_; ++n)
        acc += __bfloat162float(xh[(size_t)n * H_ + c]) + __bfloat162float(xl[(size_t)n * H_ + c]);
    pooled[(size_t)(inst0 + ci) * H_ + c] = acc * (1.0f / N_);
}

// ------------------------------------------------------------------- fc ----
__global__ __launch_bounds__(256) void fc_kernel(
    const float* __restrict__ pooled, const float* __restrict__ hf,
    const float* __restrict__ af, const float* __restrict__ fcW,
    const float* __restrict__ fcb, float* __restrict__ outp)
{
    const int idx = blockIdx.x * 256 + threadIdx.x;
    if (idx >= G_ * C_) return;
    const int gi = idx / C_;
    const int c  = idx % C_;
    float acc = fcb[c];
    const float* ph = pooled + (size_t)gi * H_;
    const float* pa = pooled + (size_t)(G_ + gi) * H_;
    for (int j = 0; j < H_; ++j) acc += ph[j] * fcW[j * C_ + c];
    for (int j = 0; j < FG; ++j) acc += hf[gi * FG + j] * fcW[(H_ + j) * C_ + c];
    for (int j = 0; j < H_; ++j) acc += pa[j] * fcW[(H_ + FG + j) * C_ + c];
    for (int j = 0; j < FG; ++j) acc += af[gi * FG + j] * fcW[(H_ + FG + H_ + j) * C_ + c];
    outp[idx] = acc;
}

// ----------------------------------------------------------------- host ----
static inline size_t align_up(size_t v, size_t a) { return (v + a - 1) & ~(a - 1); }

extern "C" void kernel_launch(void* const* d_in, const int* in_sizes, int n_in,
                              void* d_out, int out_size, void* d_ws, size_t ws_size,
                              hipStream_t stream)
{
    const float* hx  = (const float*)d_in[0];
    const float* ax  = (const float*)d_in[1];
    const int*   hei = (const int*)d_in[2];
    const int*   aei = (const int*)d_in[3];
    const float* hew = (const float*)d_in[4];
    const float* aew = (const float*)d_in[5];
    const float* hf  = (const float*)d_in[6];
    const float* af  = (const float*)d_in[7];
    const float* W0  = (const float*)d_in[8];
    const float* Wh  = (const float*)d_in[9];
    const float* bs  = (const float*)d_in[10];
    const float* fcW = (const float*)d_in[11];
    const float* fcb = (const float*)d_in[12];
    float* outp = (float*)d_out;

    const size_t pooled_b = align_up((size_t)B_ * H_ * sizeof(float), 256);
    const size_t wt_b     = align_up((size_t)(L_ - 1) * H_ * H_ * sizeof(__hip_bfloat16), 256);
    const size_t col_b  = align_up((size_t)E_ * sizeof(int), 256);
    const size_t val_b  = align_up((size_t)E_ * sizeof(float), 256);
    const size_t rp_b   = align_up((size_t)(N_ + 1) * sizeof(int), 256);
    const size_t sn_b   = align_up((size_t)N_ * sizeof(float), 256);
    const size_t h_b    = align_up((size_t)N_ * H_ * sizeof(float), 256);
    const size_t xs_b   = align_up((size_t)N_ * H_ * sizeof(__hip_bfloat16), 256);
    const size_t per_inst = col_b + val_b + rp_b + sn_b + h_b + 2 * xs_b;
    const size_t fixed = pooled_b + 2 * wt_b;

    int CB = (int)((ws_size > fixed) ? (ws_size - fixed) / per_inst : 0);
    if (CB < 1) CB = 1;
    if (CB > B_) CB = B_;

    char* p = (char*)d_ws;
    float* pooled = (float*)p;                 p += pooled_b;
    __hip_bfloat16* WThi = (__hip_bfloat16*)p; p += wt_b;
    __hip_bfloat16* WTlo = (__hip_bfloat16*)p; p += wt_b;
    int*   colv = (int*)p;                     p += (size_t)CB * col_b;
    float* valv = (float*)p;                   p += (size_t)CB * val_b;
    int*   rowptr = (int*)p;                   p += (size_t)CB * rp_b;
    float* selfnorm = (float*)p;               p += (size_t)CB * sn_b;
    float* hbuf = (float*)p;                   p += (size_t)CB * h_b;
    __hip_bfloat16* xhi = (__hip_bfloat16*)p;  p += (size_t)CB * xs_b;
    __hip_bfloat16* xlo = (__hip_bfloat16*)p;

    wsplit_kernel<<<((L_ - 1) * H_ * H_ + 255) / 256, 256, 0, stream>>>(Wh, WThi, WTlo);

    for (int i0 = 0; i0 < B_; i0 += CB) {
        const int cb = (B_ - i0 < CB) ? (B_ - i0) : CB;

        prep_kernel<<<cb, 256, 0, stream>>>(hei, aei, hew, aew, i0,
                                            colv, valv, rowptr, selfnorm);
        xw0_kernel<<<cb * 32, 256, 0, stream>>>(hx, ax, W0, i0, hbuf);

        for (int l = 0; l < L_; ++l) {
            if (l > 0) {
                gemm_mfma_kernel<<<cb * 8, 256, 0, stream>>>(
                    xhi, xlo,
                    WThi + (size_t)(l - 1) * H_ * H_,
                    WTlo + (size_t)(l - 1) * H_ * H_,
                    hbuf);
            }
            agg_kernel<<<cb * 4, 512, 0, stream>>>(
                hbuf, colv, valv, rowptr, selfnorm, bs + (size_t)l * H_, xhi, xlo);
        }
        pool_kernel<<<cb, 256, 0, stream>>>(xhi, xlo, i0, pooled);
    }

    fc_kernel<<<(G_ * C_ + 255) / 256, 256, 0, stream>>>(pooled, hf, af, fcW, fcb, outp);
}

// Round 5
// 5134.714 us; speedup vs baseline: 2.1878x; 1.6360x over previous
//
#include <hip/hip_runtime.h>
#include <hip/hip_bf16.h>

// ProductGraphsModel: 2x256 independent 5-layer GCN stacks + mean-pool + FC.
// Round 5:
//  - agg: 1024 thr (16 waves x 32 rows), 4-acc x8-unroll edge loop,
//    self-loop folded into CSR. 2x occupancy + ILP on the ds_read chain.
//  - GEMM: single packed-K GEMM (K=768 = [hi|lo|hi] x [Whi;Whi;Wlo]),
//    BK=32, 32KB LDS -> ~3 blocks/CU implicit pipeline overlap.
//  - pool: 4-way ILP, reads packed hi/lo.

#define G_   256
#define N_   512
#define E_   16384
#define ET_  (E_ + N_)   // edges + self-loops
#define H_   256
#define KP_  768         // packed K = 3*H
#define FIN  4
#define FG   6
#define C_   3
#define L_   5
#define B_   512   // 2*G_ instances (home then away)

typedef __attribute__((ext_vector_type(4))) float f32x4;
typedef __attribute__((ext_vector_type(8))) short bf16x8;

__device__ __forceinline__ void gload_lds16(const void* g, void* l) {
    __builtin_amdgcn_global_load_lds(
        (const __attribute__((address_space(1))) void*)g,
        (__attribute__((address_space(3))) void*)l, 16, 0, 0);
}

// m204 bijective chunked swizzle: orig%8 = HW XCD.
__device__ __forceinline__ int xcd_chunk_swizzle(int orig, int nwg) {
    const int q = nwg >> 3, r = nwg & 7, x = orig & 7;
    const int base = (x < r) ? x * (q + 1) : r * (q + 1) + (x - r) * q;
    return base + (orig >> 3);
}

// ---------------------------------------------------------------- prep ----
// CSR by dst with self-loop at slot rowptr[t] (val = dinv^2, col = t).
__global__ __launch_bounds__(256) void prep_kernel(
    const int* __restrict__ hei, const int* __restrict__ aei,
    const float* __restrict__ hew, const float* __restrict__ aew,
    int inst0,
    int* __restrict__ colv, float* __restrict__ valv, int* __restrict__ rowptr)
{
    const int ci = blockIdx.x;
    const int b  = inst0 + ci;
    const int g  = (b < G_) ? b : b - G_;
    const int*   ei = ((b < G_) ? hei : aei) + (size_t)g * 2 * E_;
    const float* ew = ((b < G_) ? hew : aew) + (size_t)g * E_;
    const int* srcA = ei;
    const int* dstA = ei + E_;

    __shared__ float degS[N_];
    __shared__ int   cntS[N_];
    __shared__ int   startS[N_ + 1];
    __shared__ int   curS[N_];
    const int tid = threadIdx.x;

    for (int n = tid; n < N_; n += 256) { degS[n] = 1.0f; cntS[n] = 0; }  // self weight 1
    __syncthreads();
    for (int e = tid; e < E_; e += 256) {
        atomicAdd(&degS[dstA[e]], ew[e]);
        atomicAdd(&cntS[dstA[e]], 1);
    }
    __syncthreads();
    for (int n = tid; n < N_; n += 256) degS[n] = rsqrtf(degS[n]);   // dinv
    __syncthreads();
    if (tid == 0) {
        int acc = 0;
        for (int n = 0; n < N_; ++n) { startS[n] = acc; acc += cntS[n] + 1; }
        startS[N_] = acc;    // = ET_
    }
    __syncthreads();
    for (int n = tid; n <= N_; n += 256) rowptr[(size_t)ci * (N_ + 1) + n] = startS[n];
    for (int n = tid; n < N_; n += 256) {
        curS[n] = 1;                                   // slot 0 = self loop
        colv[(size_t)ci * ET_ + startS[n]] = n;
        valv[(size_t)ci * ET_ + startS[n]] = degS[n] * degS[n];
    }
    __syncthreads();
    for (int e = tid; e < E_; e += 256) {
        int t = dstA[e], s = srcA[e];
        int pos = startS[t] + atomicAdd(&curS[t], 1);
        colv[(size_t)ci * ET_ + pos] = s;
        valv[(size_t)ci * ET_ + pos] = degS[s] * ew[e] * degS[t];
    }
}

// ------------------------------------------------ W transpose + pack ----
// Wh[l][k][n] fp32 -> WTpack[l][n][768] bf16: [k]=hi, [256+k]=hi, [512+k]=lo.
__global__ __launch_bounds__(256) void wsplit_kernel(
    const float* __restrict__ Wh, __hip_bfloat16* __restrict__ WTpack)
{
    const int idx = blockIdx.x * 256 + threadIdx.x;
    if (idx >= (L_ - 1) * H_ * H_) return;
    const int l = idx >> 16, rem = idx & 65535;
    const int n = rem >> 8, k = rem & 255;
    const float w = Wh[(size_t)l * H_ * H_ + (size_t)k * H_ + n];
    const __hip_bfloat16 hi = __float2bfloat16(w);
    const __hip_bfloat16 lo = __float2bfloat16(w - __bfloat162float(hi));
    __hip_bfloat16* base = WTpack + ((size_t)(l * H_ + n)) * KP_;
    base[k] = hi; base[H_ + k] = hi; base[2 * H_ + k] = lo;
}

// ---------------------------------------------------- layer-0 transform ----
__global__ __launch_bounds__(256) void xw0_kernel(
    const float* __restrict__ hx, const float* __restrict__ ax,
    const float* __restrict__ W0, int inst0, float* __restrict__ h0)
{
    const int ci = blockIdx.x >> 5;
    const int n0 = (blockIdx.x & 31) << 4;
    const int c  = threadIdx.x;
    const int b  = inst0 + ci;
    const int g  = (b < G_) ? b : b - G_;
    const float w0 = W0[c], w1 = W0[H_ + c], w2 = W0[2 * H_ + c], w3 = W0[3 * H_ + c];
    const float* x = ((b < G_) ? hx : ax) + ((size_t)g * N_ + n0) * FIN;
    float* o = h0 + (((size_t)ci * N_ + n0) << 8) + c;
#pragma unroll
    for (int i = 0; i < 16; ++i) {
        const float4 xv = *(const float4*)&x[i * 4];
        float acc = xv.x * w0;
        acc = fmaf(xv.y, w1, acc);
        acc = fmaf(xv.z, w2, acc);
        acc = fmaf(xv.w, w3, acc);
        o[(size_t)i << 8] = acc;
    }
}

// ----------------------------------------------------- packed MFMA GEMM ----
// C[M,256] = Apack[M,768] @ WTpack^T. BM=BN=128, BK=32, 256 thr (2x2 waves),
// double-buffered 32KB LDS -> ~3 blocks/CU overlap the barrier drains.
__global__ __launch_bounds__(256, 3) void gemm_mfma_kernel(
    const short* __restrict__ A,     // [M][768] bf16 bits
    const short* __restrict__ B,     // [256][768] bf16 bits
    float* __restrict__ Cout)        // [M][256]
{
    __shared__ short lA[2][4096];    // [buf][(kb*128+row)*8+j] : 8 KiB/buf
    __shared__ short lB[2][4096];

    const int tid  = threadIdx.x;
    const int w    = xcd_chunk_swizzle(blockIdx.x, gridDim.x);
    const int m0   = (w >> 1) * 128;
    const int n0   = (w & 1) * 128;
    const int lane = tid & 63;
    const int wave = tid >> 6;
    const int wm   = (wave >> 1) * 64;
    const int wn   = (wave & 1) * 64;
    const int l15  = lane & 15;
    const int kb4  = lane >> 4;

    f32x4 acc[4][4];
#pragma unroll
    for (int i = 0; i < 4; ++i)
#pragma unroll
        for (int j = 0; j < 4; ++j) acc[i][j] = (f32x4)0.f;

#define STG(buf, k0) do { \
    _Pragma("unroll") for (int call = 0; call < 2; ++call) { \
        const int c = call * 256 + tid; \
        const int row = c & 127, kb = c >> 7; \
        gload_lds16(A + (size_t)(m0 + row) * KP_ + (k0) + (kb << 3), \
                    &lA[buf][(c & ~63) << 3]); \
        gload_lds16(B + (size_t)(n0 + row) * KP_ + (k0) + (kb << 3), \
                    &lB[buf][(c & ~63) << 3]); \
    } } while (0)

#define COMP(buf) do { \
    bf16x8 av[4]; \
    _Pragma("unroll") for (int mf = 0; mf < 4; ++mf) \
        av[mf] = *(const bf16x8*)&lA[buf][(kb4 * 128 + wm + mf * 16 + l15) << 3]; \
    _Pragma("unroll") for (int nf = 0; nf < 4; ++nf) { \
        const bf16x8 bv = *(const bf16x8*)&lB[buf][(kb4 * 128 + wn + nf * 16 + l15) << 3]; \
        _Pragma("unroll") for (int mf = 0; mf < 4; ++mf) \
            acc[mf][nf] = __builtin_amdgcn_mfma_f32_16x16x32_bf16(av[mf], bv, acc[mf][nf], 0, 0, 0); \
    } } while (0)

    STG(0, 0);
    __syncthreads();
#pragma unroll
    for (int st = 0; st < 23; ++st) {
        STG((st + 1) & 1, (st + 1) * 32);   // async next K-step
        COMP(st & 1);                       // compute current
        __syncthreads();                    // vmcnt+lgkm drained: next ready
    }
    COMP(1);

#pragma unroll
    for (int mf = 0; mf < 4; ++mf) {
        const int r0 = m0 + wm + mf * 16 + (kb4 << 2);
#pragma unroll
        for (int nf = 0; nf < 4; ++nf) {
            const int col = n0 + wn + nf * 16 + l15;
            const f32x4 v = acc[mf][nf];
#pragma unroll
            for (int j = 0; j < 4; ++j)
                Cout[((size_t)(r0 + j) << 8) + col] = v[j];
        }
    }
#undef STG
#undef COMP
}

// ---------------------------------------------------------- aggregation ----
// block = (instance, 64-ch chunk), 1024 thr (16 waves x 32 rows).
// h[:, chunk] staged in 128 KiB LDS; per row: coalesced 64-edge load +
// readlane broadcast, x8 unroll into 4 accumulators. Self-loop is in CSR.
// Output written as packed bf16 [hi | lo | hi] rows for the K=768 GEMM.
__global__ __launch_bounds__(1024, 4) void agg_kernel(
    const float* __restrict__ h, const int* __restrict__ colv,
    const float* __restrict__ valv, const int* __restrict__ rowptr,
    const float* __restrict__ bias, __hip_bfloat16* __restrict__ xpack)
{
    __shared__ float hs[N_ * 64];   // 128 KiB: hs[n][c]
    const int w    = xcd_chunk_swizzle(blockIdx.x, gridDim.x);
    const int ci   = w >> 2;
    const int c0   = (w & 3) << 6;
    const int tid  = threadIdx.x;
    const int lane = tid & 63;
    const int wv   = tid >> 6;

    const float* hb = h + (size_t)ci * N_ * H_;
#pragma unroll
    for (int it = 0; it < 8; ++it) {            // 8192 16B chunks / 1024 thr
        const int i  = it * 1024 + tid;
        const int n  = i >> 4;
        const int c4 = (i & 15) << 2;
        gload_lds16(hb + (size_t)n * H_ + c0 + c4, &hs[(i & ~63) << 2]);
    }
    __syncthreads();

    const int*   rp = rowptr + (size_t)ci * (N_ + 1);
    const int*   cv = colv + (size_t)ci * ET_;
    const float* vv = valv + (size_t)ci * ET_;
    const float bval = bias[c0 + lane];

    for (int t = wv * 32; t < wv * 32 + 32; ++t) {
        const int r0 = rp[t], r1 = rp[t + 1];
        float a0 = 0.f, a1 = 0.f, a2 = 0.f, a3 = 0.f;
        for (int e0 = r0; e0 < r1; e0 += 64) {
            const int rem = r1 - e0;
            const int cnt = rem < 64 ? rem : 64;
            int mc = 0, mv = 0;
            if (lane < rem) {
                mc = cv[e0 + lane];
                mv = (int)__float_as_uint(vv[e0 + lane]);
            }
            int i = 0;
            for (; i + 8 <= cnt; i += 8) {
                const int s0 = __builtin_amdgcn_readlane(mc, i + 0);
                const int s1 = __builtin_amdgcn_readlane(mc, i + 1);
                const int s2 = __builtin_amdgcn_readlane(mc, i + 2);
                const int s3 = __builtin_amdgcn_readlane(mc, i + 3);
                const int s4 = __builtin_amdgcn_readlane(mc, i + 4);
                const int s5 = __builtin_amdgcn_readlane(mc, i + 5);
                const int s6 = __builtin_amdgcn_readlane(mc, i + 6);
                const int s7 = __builtin_amdgcn_readlane(mc, i + 7);
                const float w0 = __uint_as_float((unsigned)__builtin_amdgcn_readlane(mv, i + 0));
                const float w1 = __uint_as_float((unsigned)__builtin_amdgcn_readlane(mv, i + 1));
                const float w2 = __uint_as_float((unsigned)__builtin_amdgcn_readlane(mv, i + 2));
                const float w3 = __uint_as_float((unsigned)__builtin_amdgcn_readlane(mv, i + 3));
                const float w4 = __uint_as_float((unsigned)__builtin_amdgcn_readlane(mv, i + 4));
                const float w5 = __uint_as_float((unsigned)__builtin_amdgcn_readlane(mv, i + 5));
                const float w6 = __uint_as_float((unsigned)__builtin_amdgcn_readlane(mv, i + 6));
                const float w7 = __uint_as_float((unsigned)__builtin_amdgcn_readlane(mv, i + 7));
                const float h0 = hs[s0 * 64 + lane];
                const float h1 = hs[s1 * 64 + lane];
                const float h2 = hs[s2 * 64 + lane];
                const float h3 = hs[s3 * 64 + lane];
                const float h4 = hs[s4 * 64 + lane];
                const float h5 = hs[s5 * 64 + lane];
                const float h6 = hs[s6 * 64 + lane];
                const float h7 = hs[s7 * 64 + lane];
                a0 = fmaf(w0, h0, a0); a1 = fmaf(w1, h1, a1);
                a2 = fmaf(w2, h2, a2); a3 = fmaf(w3, h3, a3);
                a0 = fmaf(w4, h4, a0); a1 = fmaf(w5, h5, a1);
                a2 = fmaf(w6, h6, a2); a3 = fmaf(w7, h7, a3);
            }
            for (; i < cnt; ++i) {
                const int s = __builtin_amdgcn_readlane(mc, i);
                const float wv_ = __uint_as_float((unsigned)__builtin_amdgcn_readlane(mv, i));
                a0 = fmaf(wv_, hs[s * 64 + lane], a0);
            }
        }
        const float o = fmaxf(a0 + a1 + a2 + a3 + bval, 0.f);
        const __hip_bfloat16 hi = __float2bfloat16(o);
        const __hip_bfloat16 lo = __float2bfloat16(o - __bfloat162float(hi));
        __hip_bfloat16* xr = xpack + ((size_t)ci * N_ + t) * KP_ + c0 + lane;
        xr[0] = hi; xr[H_] = lo; xr[2 * H_] = hi;
    }
}

// ----------------------------------------------------------------- pool ----
__global__ __launch_bounds__(256) void pool_kernel(
    const __hip_bfloat16* __restrict__ xpack, int inst0, float* __restrict__ pooled)
{
    const int ci = blockIdx.x;
    const int c  = threadIdx.x;
    const __hip_bfloat16* xp = xpack + (size_t)ci * N_ * KP_;
    float a0 = 0.f, a1 = 0.f, a2 = 0.f, a3 = 0.f;
    for (int n = 0; n < N_; n += 4) {
        a0 += __bfloat162float(xp[(size_t)(n + 0) * KP_ + c]) + __bfloat162float(xp[(size_t)(n + 0) * KP_ + H_ + c]);
        a1 += __bfloat162float(xp[(size_t)(n + 1) * KP_ + c]) + __bfloat162float(xp[(size_t)(n + 1) * KP_ + H_ + c]);
        a2 += __bfloat162float(xp[(size_t)(n + 2) * KP_ + c]) + __bfloat162float(xp[(size_t)(n + 2) * KP_ + H_ + c]);
        a3 += __bfloat162float(xp[(size_t)(n + 3) * KP_ + c]) + __bfloat162float(xp[(size_t)(n + 3) * KP_ + H_ + c]);
    }
    pooled[(size_t)(inst0 + ci) * H_ + c] = (a0 + a1 + a2 + a3) * (1.0f / N_);
}

// ------------------------------------------------------------------- fc ----
__global__ __launch_bounds__(256) void fc_kernel(
    const float* __restrict__ pooled, const float* __restrict__ hf,
    const float* __restrict__ af, const float* __restrict__ fcW,
    const float* __restrict__ fcb, float* __restrict__ outp)
{
    const int idx = blockIdx.x * 256 + threadIdx.x;
    if (idx >= G_ * C_) return;
    const int gi = idx / C_;
    const int c  = idx % C_;
    float acc = fcb[c];
    const float* ph = pooled + (size_t)gi * H_;
    const float* pa = pooled + (size_t)(G_ + gi) * H_;
    for (int j = 0; j < H_; ++j) acc += ph[j] * fcW[j * C_ + c];
    for (int j = 0; j < FG; ++j) acc += hf[gi * FG + j] * fcW[(H_ + j) * C_ + c];
    for (int j = 0; j < H_; ++j) acc += pa[j] * fcW[(H_ + FG + j) * C_ + c];
    for (int j = 0; j < FG; ++j) acc += af[gi * FG + j] * fcW[(H_ + FG + H_ + j) * C_ + c];
    outp[idx] = acc;
}

// ----------------------------------------------------------------- host ----
static inline size_t align_up(size_t v, size_t a) { return (v + a - 1) & ~(a - 1); }

extern "C" void kernel_launch(void* const* d_in, const int* in_sizes, int n_in,
                              void* d_out, int out_size, void* d_ws, size_t ws_size,
                              hipStream_t stream)
{
    const float* hx  = (const float*)d_in[0];
    const float* ax  = (const float*)d_in[1];
    const int*   hei = (const int*)d_in[2];
    const int*   aei = (const int*)d_in[3];
    const float* hew = (const float*)d_in[4];
    const float* aew = (const float*)d_in[5];
    const float* hf  = (const float*)d_in[6];
    const float* af  = (const float*)d_in[7];
    const float* W0  = (const float*)d_in[8];
    const float* Wh  = (const float*)d_in[9];
    const float* bs  = (const float*)d_in[10];
    const float* fcW = (const float*)d_in[11];
    const float* fcb = (const float*)d_in[12];
    float* outp = (float*)d_out;

    const size_t pooled_b = align_up((size_t)B_ * H_ * sizeof(float), 256);
    const size_t wtp_b    = align_up((size_t)(L_ - 1) * H_ * KP_ * sizeof(__hip_bfloat16), 256);
    const size_t col_b  = align_up((size_t)ET_ * sizeof(int), 256);
    const size_t val_b  = align_up((size_t)ET_ * sizeof(float), 256);
    const size_t rp_b   = align_up((size_t)(N_ + 1) * sizeof(int), 256);
    const size_t h_b    = align_up((size_t)N_ * H_ * sizeof(float), 256);
    const size_t xp_b   = align_up((size_t)N_ * KP_ * sizeof(__hip_bfloat16), 256);
    const size_t per_inst = col_b + val_b + rp_b + h_b + xp_b;
    const size_t fixed = pooled_b + wtp_b;

    int CB = (int)((ws_size > fixed) ? (ws_size - fixed) / per_inst : 0);
    if (CB < 1) CB = 1;
    if (CB > B_) CB = B_;

    char* p = (char*)d_ws;
    float* pooled = (float*)p;                   p += pooled_b;
    __hip_bfloat16* WTpack = (__hip_bfloat16*)p; p += wtp_b;
    int*   colv = (int*)p;                       p += (size_t)CB * col_b;
    float* valv = (float*)p;                     p += (size_t)CB * val_b;
    int*   rowptr = (int*)p;                     p += (size_t)CB * rp_b;
    float* hbuf = (float*)p;                     p += (size_t)CB * h_b;
    __hip_bfloat16* xpack = (__hip_bfloat16*)p;

    wsplit_kernel<<<((L_ - 1) * H_ * H_ + 255) / 256, 256, 0, stream>>>(Wh, WTpack);

    for (int i0 = 0; i0 < B_; i0 += CB) {
        const int cb = (B_ - i0 < CB) ? (B_ - i0) : CB;

        prep_kernel<<<cb, 256, 0, stream>>>(hei, aei, hew, aew, i0, colv, valv, rowptr);
        xw0_kernel<<<cb * 32, 256, 0, stream>>>(hx, ax, W0, i0, hbuf);

        for (int l = 0; l < L_; ++l) {
            if (l > 0) {
                gemm_mfma_kernel<<<cb * 8, 256, 0, stream>>>(
                    (const short*)xpack,
                    (const short*)(WTpack + (size_t)(l - 1) * H_ * KP_),
                    hbuf);
            }
            agg_kernel<<<cb * 4, 1024, 0, stream>>>(
                hbuf, colv, valv, rowptr, bs + (size_t)l * H_, xpack);
        }
        pool_kernel<<<cb, 256, 0, stream>>>(xpack, i0, pooled);
    }

    fc_kernel<<<(G_ * C_ + 255) / 256, 256, 0, stream>>>(pooled, hf, af, fcW, fcb, outp);
}